// Round 1
// baseline (127.507 us; speedup 1.0000x reference)
//
#include <hip/hip_runtime.h>
#include <hip/hip_bf16.h>

#define HIDDEN 2048
#define GATE_ROWS (3 * HIDDEN)   // 6144
#define VOCAB 53
#define LAYERS 6

// One block per output element j (0..2047). 6 waves:
//   wave 0..2 : rows j, j+2048, j+4096 of w_ih  ·  x
//   wave 3..5 : rows j, j+2048, j+4096 of w_hh  ·  h_in
// Then thread 0 does the GRU gate math and writes h_new[j].
__global__ __launch_bounds__(384) void gru_layer_kernel(
    const float* __restrict__ w_ih,   // [6144][2048] (this layer)
    const float* __restrict__ w_hh,   // [6144][2048]
    const float* __restrict__ b_ih,   // [6144]
    const float* __restrict__ b_hh,   // [6144]
    const float* __restrict__ h_in,   // [2048]
    const float* __restrict__ x_src,  // [2048] (or emb table if token!=null)
    const int*   __restrict__ token,  // non-null only for layer 0
    float* __restrict__ h_out)        // [2048]
{
    const int j    = blockIdx.x;           // output element
    const int wave = threadIdx.x >> 6;     // 0..5
    const int lane = threadIdx.x & 63;

    const float* x = x_src;
    if (token) x += (size_t)token[0] * HIDDEN;

    const float* W = (wave < 3) ? w_ih : w_hh;
    const float* v = (wave < 3) ? x    : h_in;
    const int    g = (wave < 3) ? wave : wave - 3;
    const size_t row = (size_t)j + (size_t)g * HIDDEN;

    const float4* Wrow = (const float4*)(W + row * HIDDEN);
    const float4* vv   = (const float4*)v;

    float sum = 0.f;
    #pragma unroll
    for (int it = 0; it < HIDDEN / 4 / 64; ++it) {   // 8 iterations
        float4 wv = Wrow[lane + it * 64];
        float4 xv = vv  [lane + it * 64];
        sum += wv.x * xv.x + wv.y * xv.y + wv.z * xv.z + wv.w * xv.w;
    }
    // wave-level reduce (64 lanes)
    #pragma unroll
    for (int off = 32; off > 0; off >>= 1)
        sum += __shfl_down(sum, off, 64);

    __shared__ float red[6];
    if (lane == 0) red[wave] = sum;
    __syncthreads();

    if (threadIdx.x == 0) {
        float gi_r = red[0] + b_ih[j];
        float gi_z = red[1] + b_ih[j + HIDDEN];
        float gi_n = red[2] + b_ih[j + 2 * HIDDEN];
        float gh_r = red[3] + b_hh[j];
        float gh_z = red[4] + b_hh[j + HIDDEN];
        float gh_n = red[5] + b_hh[j + 2 * HIDDEN];

        float r = 1.f / (1.f + __expf(-(gi_r + gh_r)));
        float z = 1.f / (1.f + __expf(-(gi_z + gh_z)));
        float n = tanhf(gi_n + r * gh_n);
        h_out[j] = (1.f - z) * n + z * h_in[j];
    }
}

// logits = w_dec @ x + b_dec  (53 x 2048). One block per row.
__global__ __launch_bounds__(256) void decode_kernel(
    const float* __restrict__ w_dec,  // [53][2048]
    const float* __restrict__ b_dec,  // [53]
    const float* __restrict__ x,      // [2048]
    float* __restrict__ logits)       // [53]
{
    const int row  = blockIdx.x;
    const int wave = threadIdx.x >> 6;
    const int lane = threadIdx.x & 63;

    const float4* W  = (const float4*)(w_dec + (size_t)row * HIDDEN);
    const float4* xv = (const float4*)x;

    float sum = 0.f;
    #pragma unroll
    for (int i = threadIdx.x; i < HIDDEN / 4; i += 256) {
        float4 wv = W[i];
        float4 v  = xv[i];
        sum += wv.x * v.x + wv.y * v.y + wv.z * v.z + wv.w * v.w;
    }
    #pragma unroll
    for (int off = 32; off > 0; off >>= 1)
        sum += __shfl_down(sum, off, 64);

    __shared__ float red[4];
    if (lane == 0) red[wave] = sum;
    __syncthreads();
    if (threadIdx.x == 0)
        logits[row] = red[0] + red[1] + red[2] + red[3] + b_dec[row];
}

extern "C" void kernel_launch(void* const* d_in, const int* in_sizes, int n_in,
                              void* d_out, int out_size, void* d_ws, size_t ws_size,
                              hipStream_t stream) {
    const int*   token  = (const int*)  d_in[0];
    const float* hidden = (const float*)d_in[1];  // [6][2048]
    const float* emb    = (const float*)d_in[2];  // [53][2048]
    const float* w_ih   = (const float*)d_in[3];  // [6][6144][2048]
    const float* w_hh   = (const float*)d_in[4];
    const float* b_ih   = (const float*)d_in[5];  // [6][6144]
    const float* b_hh   = (const float*)d_in[6];
    const float* w_dec  = (const float*)d_in[7];  // [53][2048]
    const float* b_dec  = (const float*)d_in[8];  // [53]

    float* out       = (float*)d_out;
    float* logits    = out;            // [53]
    float* h_new     = out + VOCAB;    // [6][2048]

    const size_t wstride = (size_t)GATE_ROWS * HIDDEN;

    for (int l = 0; l < LAYERS; ++l) {
        const float* x_src = (l == 0) ? emb : h_new + (size_t)(l - 1) * HIDDEN;
        const int*   tok   = (l == 0) ? token : nullptr;
        gru_layer_kernel<<<HIDDEN, 384, 0, stream>>>(
            w_ih + (size_t)l * wstride,
            w_hh + (size_t)l * wstride,
            b_ih + (size_t)l * GATE_ROWS,
            b_hh + (size_t)l * GATE_ROWS,
            hidden + (size_t)l * HIDDEN,
            x_src, tok,
            h_new + (size_t)l * HIDDEN);
    }

    decode_kernel<<<VOCAB, 256, 0, stream>>>(
        w_dec, b_dec, h_new + (size_t)(LAYERS - 1) * HIDDEN, logits);
}